// Round 1
// baseline (5249.183 us; speedup 1.0000x reference)
//
#include <hip/hip_runtime.h>
#include <math.h>

// Problem constants (from reference)
constexpr int BB = 2;          // batch
constexpr int CC = 128;        // DIM
constexpr int HH = 96, WW = 96;
constexpr int PP = HH * WW;    // 9216 pixels per image
constexpr int P4 = PP / 4;     // 2304 float4 per channel-plane
constexpr int NHEADS = 8;
constexpr int HD = 16;         // channels per head

// ---------------------------------------------------------------------------
// conv1x1: out[b,o,p] = sum_i w[o,i]*in[b,i,p] (+bias[o]) (+resid[b,o,p])
// scaleq: multiply first 128 output channels by 0.25 (q scaling for qkv)
// float4-vectorized over pixels.
// ---------------------------------------------------------------------------
__global__ __launch_bounds__(256)
void k_conv1x1(const float* __restrict__ in, const float* __restrict__ w,
               const float* __restrict__ bias, const float* __restrict__ resid,
               float* __restrict__ out, int Cin, int Cout, int scaleq)
{
    int gid = blockIdx.x * blockDim.x + threadIdx.x;
    int total = BB * Cout * P4;
    if (gid >= total) return;
    int p4 = gid % P4;
    int o  = (gid / P4) % Cout;
    int b  = gid / (P4 * Cout);

    const float* wo = w + (size_t)o * Cin;
    const float4* inb = reinterpret_cast<const float4*>(in) + (size_t)b * Cin * P4 + p4;

    float ax = 0.f, ay = 0.f, az = 0.f, aw = 0.f;
    #pragma unroll 4
    for (int i = 0; i < Cin; ++i) {
        float wv = wo[i];
        float4 xv = inb[(size_t)i * P4];
        ax = fmaf(wv, xv.x, ax);
        ay = fmaf(wv, xv.y, ay);
        az = fmaf(wv, xv.z, az);
        aw = fmaf(wv, xv.w, aw);
    }
    if (scaleq && o < CC) { ax *= 0.25f; ay *= 0.25f; az *= 0.25f; aw *= 0.25f; }
    if (bias) { float bv = bias[o]; ax += bv; ay += bv; az += bv; aw += bv; }
    if (resid) {
        float4 rv = reinterpret_cast<const float4*>(resid)[(size_t)(b * Cout + o) * P4 + p4];
        ax += rv.x; ay += rv.y; az += rv.z; aw += rv.w;
    }
    float4 r; r.x = ax; r.y = ay; r.z = az; r.w = aw;
    reinterpret_cast<float4*>(out)[(size_t)(b * Cout + o) * P4 + p4] = r;
}

// ---------------------------------------------------------------------------
// Dilated 3x3 conv, 128->128, padding=D, dilation=D (templated on D).
// Block: 256 threads = 32 output channels x 8 strips of 12 columns.
// Grid: BB * HH * 4 (o-tiles).
// ---------------------------------------------------------------------------
template<int D>
__global__ __launch_bounds__(256)
void k_conv3x3(const float* __restrict__ in, const float* __restrict__ w,
               const float* __restrict__ bias, float* __restrict__ out)
{
    int blk = blockIdx.x;
    int otile = blk % 4;
    int i     = (blk / 4) % HH;
    int b     = blk / (4 * HH);
    int t = threadIdx.x;
    int o  = otile * 32 + (t >> 3);
    int j0 = (t & 7) * 12;

    float acc[12];
    #pragma unroll
    for (int jj = 0; jj < 12; ++jj) acc[jj] = 0.f;

    const float* wbase = w + (size_t)o * CC * 9;
    for (int c = 0; c < CC; ++c) {
        const float* wc = wbase + c * 9;
        #pragma unroll
        for (int dy = 0; dy < 3; ++dy) {
            int row = i + (dy - 1) * D;
            if (row < 0 || row >= HH) continue;  // zero padding: contributes 0
            const float* rp = in + ((size_t)(b * CC + c) * HH + row) * WW;
            float r[12 + 2 * D];
            #pragma unroll
            for (int u = 0; u < 12 + 2 * D; ++u) {
                int col = j0 - D + u;
                r[u] = (col >= 0 && col < WW) ? rp[col] : 0.f;
            }
            float w0 = wc[dy * 3 + 0], w1 = wc[dy * 3 + 1], w2 = wc[dy * 3 + 2];
            #pragma unroll
            for (int jj = 0; jj < 12; ++jj) {
                acc[jj] = fmaf(w0, r[jj],         acc[jj]);
                acc[jj] = fmaf(w1, r[jj + D],     acc[jj]);
                acc[jj] = fmaf(w2, r[jj + 2 * D], acc[jj]);
            }
        }
    }
    float bv = bias[o];
    float* op = out + ((size_t)(b * CC + o) * HH + i) * WW + j0;
    #pragma unroll
    for (int jj = 0; jj < 12; ++jj) op[jj] = acc[jj] + bv;
}

// ---------------------------------------------------------------------------
// BatchNorm training-mode stats: per channel mean + rsqrt(var+eps)
// One block (256 threads) per channel; biased variance over B*H*W.
// stats layout: [0..127]=mean, [128..255]=rstd
// ---------------------------------------------------------------------------
__global__ __launch_bounds__(256)
void k_bnstats(const float* __restrict__ x, float* __restrict__ stats)
{
    int c = blockIdx.x;
    int t = threadIdx.x;
    float s = 0.f, s2 = 0.f;
    for (int b = 0; b < BB; ++b) {
        const float* xp = x + (size_t)(b * CC + c) * PP;
        for (int p = t; p < PP; p += 256) {
            float v = xp[p];
            s += v; s2 += v * v;
        }
    }
    #pragma unroll
    for (int off = 32; off > 0; off >>= 1) {
        s  += __shfl_down(s,  off);
        s2 += __shfl_down(s2, off);
    }
    __shared__ float ls[4], ls2[4];
    int wid = t >> 6, lane = t & 63;
    if (lane == 0) { ls[wid] = s; ls2[wid] = s2; }
    __syncthreads();
    if (t == 0) {
        float S = 0.f, S2 = 0.f;
        #pragma unroll
        for (int wv = 0; wv < 4; ++wv) { S += ls[wv]; S2 += ls2[wv]; }
        const float inv = 1.f / (float)(BB * PP);
        float mu  = S * inv;
        float var = S2 * inv - mu * mu;
        stats[c]      = mu;
        stats[CC + c] = rsqrtf(var + 1e-5f);
    }
}

// ---------------------------------------------------------------------------
// Fused BN(apply) + ReLU, float4 elementwise.
// ---------------------------------------------------------------------------
__global__ __launch_bounds__(256)
void k_bnrelu(const float* __restrict__ x, const float* __restrict__ stats,
              const float* __restrict__ g, const float* __restrict__ bta,
              float* __restrict__ out)
{
    int gid = blockIdx.x * blockDim.x + threadIdx.x;
    int total = BB * CC * P4;
    if (gid >= total) return;
    int c = (gid / P4) % CC;
    float mu = stats[c], rs = stats[CC + c];
    float sc = rs * g[c];
    float sh = bta[c] - mu * sc;
    float4 v = reinterpret_cast<const float4*>(x)[gid];
    v.x = fmaxf(fmaf(v.x, sc, sh), 0.f);
    v.y = fmaxf(fmaf(v.y, sc, sh), 0.f);
    v.z = fmaxf(fmaf(v.z, sc, sh), 0.f);
    v.w = fmaxf(fmaf(v.w, sc, sh), 0.f);
    reinterpret_cast<float4*>(out)[gid] = v;
}

// ---------------------------------------------------------------------------
// Local channel self-attention. One thread per (b, head, pixel).
// dots[n,m] = sum over 3x3 neighborhood (zero-padded) of Q[n]*K[m]
// softmax over m; out[n] = sum_m attn[n,m] * boxsum3x3(V[m])
// qkv layout: (B, 384, H, W) with q=[0,128), k=[128,256), v=[256,384).
// Q already scaled by 0.25 in the qkv conv.
// ---------------------------------------------------------------------------
__global__ __launch_bounds__(256)
void k_attn(const float* __restrict__ qkv, float* __restrict__ out)
{
    int gid = blockIdx.x * blockDim.x + threadIdx.x;
    int total = BB * NHEADS * PP;
    if (gid >= total) return;
    int p    = gid % PP;
    int head = (gid / PP) % NHEADS;
    int b    = gid / (PP * NHEADS);
    int i = p / WW, j = p % WW;

    const float* qb = qkv + ((size_t)b * 384 +       head * HD) * PP;
    const float* kb = qkv + ((size_t)b * 384 + 128 + head * HD) * PP;
    const float* vb = qkv + ((size_t)b * 384 + 256 + head * HD) * PP;

    int  off[9];
    bool val[9];
    #pragma unroll
    for (int dy = 0; dy < 3; ++dy) {
        #pragma unroll
        for (int dx = 0; dx < 3; ++dx) {
            int ii = i + dy - 1, jj = j + dx - 1;
            int kk = dy * 3 + dx;
            val[kk] = (ii >= 0 && ii < HH && jj >= 0 && jj < WW);
            off[kk] = ii * WW + jj;
        }
    }

    // box sums of V
    float vs[HD];
    #pragma unroll
    for (int m = 0; m < HD; ++m) {
        const float* vm = vb + (size_t)m * PP;
        float s = 0.f;
        #pragma unroll
        for (int kk = 0; kk < 9; ++kk) if (val[kk]) s += vm[off[kk]];
        vs[m] = s;
    }

    float* ob = out + ((size_t)(b * CC) + head * HD) * PP + p;
    for (int n = 0; n < HD; ++n) {
        float qn[9];
        const float* qp = qb + (size_t)n * PP;
        #pragma unroll
        for (int kk = 0; kk < 9; ++kk) qn[kk] = val[kk] ? qp[off[kk]] : 0.f;

        float dots[HD];
        float mx = -1e30f;
        #pragma unroll
        for (int m = 0; m < HD; ++m) {
            const float* km = kb + (size_t)m * PP;
            float s = 0.f;
            #pragma unroll
            for (int kk = 0; kk < 9; ++kk) if (val[kk]) s = fmaf(qn[kk], km[off[kk]], s);
            dots[m] = s;
            mx = fmaxf(mx, s);
        }
        float den = 0.f, o_ = 0.f;
        #pragma unroll
        for (int m = 0; m < HD; ++m) {
            float e = __expf(dots[m] - mx);
            den += e;
            o_  = fmaf(e, vs[m], o_);
        }
        ob[(size_t)n * PP] = o_ / den;
    }
}

// ---------------------------------------------------------------------------
extern "C" void kernel_launch(void* const* d_in, const int* in_sizes, int n_in,
                              void* d_out, int out_size, void* d_ws, size_t ws_size,
                              hipStream_t stream)
{
    const float* x      = (const float*)d_in[0];
    const float* w_in   = (const float*)d_in[1];
    const float* b_in   = (const float*)d_in[2];
    const float* conv_w = (const float*)d_in[3];
    const float* conv_b = (const float*)d_in[4];
    const float* bn_g   = (const float*)d_in[5];
    const float* bn_b   = (const float*)d_in[6];
    const float* qkv_w  = (const float*)d_in[7];
    const float* fc_w   = (const float*)d_in[8];
    const float* fc_b   = (const float*)d_in[9];
    const float* w_out  = (const float*)d_in[10];
    const float* b_out  = (const float*)d_in[11];
    float* out = (float*)d_out;

    float* ws = (float*)d_ws;
    const size_t NA = (size_t)BB * CC * PP;       // 2,359,296 floats
    float* bufA  = ws;
    float* bufB  = bufA + NA;
    float* bufD  = bufB + NA;
    float* qkvB  = bufD + NA;                     // B*384*PP = 7,077,888 floats
    float* stats = qkvB + (size_t)BB * 384 * PP;  // 256 floats

    // Input projection 64 -> 128
    {
        int total = BB * CC * P4;
        k_conv1x1<<<(total + 255) / 256, 256, 0, stream>>>(
            x, w_in, b_in, nullptr, bufA, 64, CC, 0);
    }

    float* h     = bufA;   // current activation
    float* other = bufB;   // scratch / next activation

    for (int L = 0; L < 4; ++L) {
        // 1) dilated conv3x3: h -> other
        const float* wL = conv_w + (size_t)L * CC * CC * 9;
        const float* bL = conv_b + (size_t)L * CC;
        dim3 g3(BB * HH * 4);
        switch (1 << L) {
            case 1: k_conv3x3<1><<<g3, 256, 0, stream>>>(h, wL, bL, other); break;
            case 2: k_conv3x3<2><<<g3, 256, 0, stream>>>(h, wL, bL, other); break;
            case 4: k_conv3x3<4><<<g3, 256, 0, stream>>>(h, wL, bL, other); break;
            case 8: k_conv3x3<8><<<g3, 256, 0, stream>>>(h, wL, bL, other); break;
        }

        // 2) BN stats over (B,H,W) per channel
        k_bnstats<<<CC, 256, 0, stream>>>(other, stats);

        // 3) BN apply + ReLU: other -> h  (old h is dead)
        {
            int total = BB * CC * P4;
            k_bnrelu<<<(total + 255) / 256, 256, 0, stream>>>(
                other, stats, bn_g + (size_t)L * CC, bn_b + (size_t)L * CC, h);
        }

        // 4) qkv projection 128 -> 384 (q scaled by 0.25): h -> qkvB
        {
            int total = BB * 384 * P4;
            k_conv1x1<<<(total + 255) / 256, 256, 0, stream>>>(
                h, qkv_w + (size_t)L * 384 * CC, nullptr, nullptr, qkvB, CC, 384, 1);
        }

        // 5) local attention: qkvB -> bufD
        {
            int total = BB * NHEADS * PP;
            k_attn<<<(total + 255) / 256, 256, 0, stream>>>(qkvB, bufD);
        }

        // 6) fc 128->128 + bias + residual(h): bufD -> other ; then swap
        {
            int total = BB * CC * P4;
            k_conv1x1<<<(total + 255) / 256, 256, 0, stream>>>(
                bufD, fc_w + (size_t)L * CC * CC, fc_b + (size_t)L * CC, h, other, CC, CC, 0);
        }
        float* tmp = h; h = other; other = tmp;
    }

    // Output projection 128 -> 64
    {
        int total = BB * 64 * P4;
        k_conv1x1<<<(total + 255) / 256, 256, 0, stream>>>(
            h, w_out, b_out, nullptr, out, CC, 64, 0);
    }
}

// Round 2
// 1530.236 us; speedup vs baseline: 3.4303x; 3.4303x over previous
//
#include <hip/hip_runtime.h>
#include <math.h>

typedef __attribute__((ext_vector_type(8))) short bf16x8;
typedef __attribute__((ext_vector_type(4))) float f32x4;
typedef __attribute__((ext_vector_type(4))) unsigned short us4;
typedef __attribute__((ext_vector_type(8))) unsigned short us8;
typedef unsigned short ushortt;

constexpr int BB = 2;
constexpr int CC = 128;
constexpr int HH = 96, WW = 96;
constexpr int PP = HH * WW;        // 9216
constexpr int NN = BB * PP;        // 18432 pixels total
constexpr int NHEADS = 8;

__device__ __forceinline__ float bf2f(unsigned short u) {
    return __uint_as_float(((unsigned)u) << 16);
}
__device__ __forceinline__ unsigned short f2bf(float f) {
    unsigned u = __float_as_uint(f);
    unsigned r = u + 0x7fff + ((u >> 16) & 1);
    return (unsigned short)(r >> 16);
}

// ---------------------------------------------------------------------------
// Weight conversion / reordering to bf16 (one dispatch).
// conv_w[L][o][c][ky][kx] -> wcv[L][o][t*128+c]  (t = ky*3+kx)
// qkv_w -> bf16 with q-rows (o<128) scaled by 0.25
// fc_w, w_in, w_out -> bf16 direct
// ---------------------------------------------------------------------------
__global__ __launch_bounds__(256)
void k_wconv(const float* __restrict__ conv_w, const float* __restrict__ qkv_w,
             const float* __restrict__ fc_w, const float* __restrict__ w_in,
             const float* __restrict__ w_out,
             unsigned short* __restrict__ wcv, unsigned short* __restrict__ wqkv,
             unsigned short* __restrict__ wfc, unsigned short* __restrict__ wi,
             unsigned short* __restrict__ wo)
{
    int gid = blockIdx.x * 256 + threadIdx.x;
    if (gid < 589824) {                       // conv permute
        int L = gid / 147456, r = gid % 147456;
        int o = r / 1152, k = r % 1152;
        int t = k / 128, c = k % 128;
        float v = conv_w[(((size_t)(L * 128 + o) * 128 + c) * 9) + t];
        wcv[gid] = f2bf(v);
    } else if (gid < 786432) {                // qkv (+q scale)
        int g = gid - 589824;
        int o = (g % 49152) / 128;
        float v = qkv_w[g] * (o < 128 ? 0.25f : 1.0f);
        wqkv[g] = f2bf(v);
    } else if (gid < 851968) {                // fc
        int g = gid - 786432;
        wfc[g] = f2bf(fc_w[g]);
    } else if (gid < 860160) {                // w_in
        int g = gid - 851968;
        wi[g] = f2bf(w_in[g]);
    } else if (gid < 868352) {                // w_out
        int g = gid - 860160;
        wo[g] = f2bf(w_out[g]);
    }
}

// x (fp32 [b][64][9216]) -> xT (bf16 [n][64])
__global__ __launch_bounds__(256)
void k_xconv(const float* __restrict__ x, unsigned short* __restrict__ xT)
{
    int n = blockIdx.x * 256 + threadIdx.x;   // 18432 threads
    int b = n / PP, p = n - b * PP;
    unsigned short* dst = xT + (size_t)n * 64;
    #pragma unroll
    for (int cg = 0; cg < 16; ++cg) {
        us4 st;
        #pragma unroll
        for (int r = 0; r < 4; ++r)
            st[r] = f2bf(x[((size_t)(b * 64 + cg * 4 + r)) * PP + p]);
        *reinterpret_cast<us4*>(dst + cg * 4) = st;
    }
}

// ---------------------------------------------------------------------------
// MFMA GEMM: out[o][n] = sum_k W[o][k] * act[n][k]   (act stored [n][Cin] bf16)
// Wave tile 64(M) x 96(N); block = WM x WN waves.
// MODE 0: bf16 out [n][Cout] (+bias if non-null)
// MODE 1: f32 out  [n][Cout]           (conv pre-BN; bias dropped — BN absorbs)
// MODE 2: bf16 out [n][Cout] + bias + bf16 residual [n][Cout]
// MODE 3: f32 out  [b][Cout][9216] scatter + bias   (final projection)
// DIL>0: implicit dilated 3x3 conv, K = 9*Cin, zero-padded via zero-page.
// ---------------------------------------------------------------------------
template<int WM, int WN, int MODE, int DIL>
__global__ __launch_bounds__(WM * WN * 64)
void k_gemm(const unsigned short* __restrict__ W,
            const unsigned short* __restrict__ act,
            const float* __restrict__ bias,
            const unsigned short* __restrict__ resid,
            void* __restrict__ outp,
            const unsigned short* __restrict__ zp,
            int Kw, int Cin, int Cout)
{
    int tid = threadIdx.x;
    int lane = tid & 63, wv = tid >> 6;
    int wm = wv % WM, wn = wv / WM;
    int l15 = lane & 15, kg = lane >> 4;

    int n_base = blockIdx.x * (WN * 96) + wn * 96;
    int o_base = blockIdx.y * (WM * 64) + wm * 64;

    const unsigned short* wbase[4];
    #pragma unroll
    for (int fm = 0; fm < 4; ++fm) {
        int o = o_base + fm * 16 + l15;
        wbase[fm] = W + (size_t)o * Kw + kg * 8;
    }

    const unsigned short* bbase[6];
    int iF[6], jF[6];
    #pragma unroll
    for (int fn = 0; fn < 6; ++fn) {
        int n = n_base + fn * 16 + l15;
        bbase[fn] = act + (size_t)n * Cin + kg * 8;
        if (DIL > 0) {
            int pix = n % PP;
            iF[fn] = pix / WW;
            jF[fn] = pix % WW;
        }
    }

    f32x4 acc[4][6];
    #pragma unroll
    for (int fm = 0; fm < 4; ++fm)
        #pragma unroll
        for (int fn = 0; fn < 6; ++fn)
            acc[fm][fn] = (f32x4){0.f, 0.f, 0.f, 0.f};

    if constexpr (DIL > 0) {
        const unsigned short* zpk = zp + kg * 8;
        for (int t = 0; t < 9; ++t) {
            int oy = (t / 3 - 1) * DIL, ox = (t % 3 - 1) * DIL;
            int disp = (oy * WW + ox) * Cin;
            const unsigned short* baddr[6];
            #pragma unroll
            for (int fn = 0; fn < 6; ++fn) {
                bool v = ((unsigned)(iF[fn] + oy) < (unsigned)HH) &&
                         ((unsigned)(jF[fn] + ox) < (unsigned)WW);
                baddr[fn] = v ? (bbase[fn] + disp) : zpk;
            }
            #pragma unroll
            for (int c0 = 0; c0 < 128; c0 += 32) {
                bf16x8 a[4], b[6];
                #pragma unroll
                for (int fm = 0; fm < 4; ++fm)
                    a[fm] = *reinterpret_cast<const bf16x8*>(wbase[fm] + t * 128 + c0);
                #pragma unroll
                for (int fn = 0; fn < 6; ++fn)
                    b[fn] = *reinterpret_cast<const bf16x8*>(baddr[fn] + c0);
                #pragma unroll
                for (int fm = 0; fm < 4; ++fm)
                    #pragma unroll
                    for (int fn = 0; fn < 6; ++fn)
                        acc[fm][fn] = __builtin_amdgcn_mfma_f32_16x16x32_bf16(
                            a[fm], b[fn], acc[fm][fn], 0, 0, 0);
            }
        }
    } else {
        #pragma unroll
        for (int k0 = 0; k0 < 128; k0 += 32) {
            if (k0 >= Cin) break;
            bf16x8 a[4], b[6];
            #pragma unroll
            for (int fm = 0; fm < 4; ++fm)
                a[fm] = *reinterpret_cast<const bf16x8*>(wbase[fm] + k0);
            #pragma unroll
            for (int fn = 0; fn < 6; ++fn)
                b[fn] = *reinterpret_cast<const bf16x8*>(bbase[fn] + k0);
            #pragma unroll
            for (int fm = 0; fm < 4; ++fm)
                #pragma unroll
                for (int fn = 0; fn < 6; ++fn)
                    acc[fm][fn] = __builtin_amdgcn_mfma_f32_16x16x32_bf16(
                        a[fm], b[fn], acc[fm][fn], 0, 0, 0);
        }
    }

    // Epilogue. D-frag: lane -> col n = l15, rows o = o_base+fm*16+kg*4+r
    #pragma unroll
    for (int fm = 0; fm < 4; ++fm) {
        #pragma unroll
        for (int fn = 0; fn < 6; ++fn) {
            f32x4 v = acc[fm][fn];
            int n = n_base + fn * 16 + l15;
            int o0 = o_base + fm * 16 + kg * 4;
            if constexpr (MODE == 1) {
                *reinterpret_cast<f32x4*>((float*)outp + (size_t)n * Cout + o0) = v;
            } else if constexpr (MODE == 0 || MODE == 2) {
                if (bias) {
                    #pragma unroll
                    for (int r = 0; r < 4; ++r) v[r] += bias[o0 + r];
                }
                if constexpr (MODE == 2) {
                    us4 rv = *reinterpret_cast<const us4*>(resid + (size_t)n * Cout + o0);
                    #pragma unroll
                    for (int r = 0; r < 4; ++r) v[r] += bf2f(rv[r]);
                }
                us4 st;
                #pragma unroll
                for (int r = 0; r < 4; ++r) st[r] = f2bf(v[r]);
                *reinterpret_cast<us4*>((unsigned short*)outp + (size_t)n * Cout + o0) = st;
            } else {
                int b_ = n / PP, p = n - b_ * PP;
                float* op = (float*)outp;
                #pragma unroll
                for (int r = 0; r < 4; ++r)
                    op[((size_t)(b_ * Cout + o0 + r)) * PP + p] = v[r] + bias[o0 + r];
            }
        }
    }
}

// ---------------------------------------------------------------------------
// BN stats stage 1: partial sums/sumsq per channel. y is f32 [n][128].
// grid 48 blocks x 256 threads; each block covers 384 n-rows.
// partials layout: [blk][ sums[128] | sumsq[128] ]
// ---------------------------------------------------------------------------
__global__ __launch_bounds__(256)
void k_bnpart(const float* __restrict__ y, float* __restrict__ partials)
{
    int t = threadIdx.x;
    int cq = t & 31, ng = t >> 5;
    int n0 = blockIdx.x * 384 + ng * 48;
    f32x4 s = {0.f, 0.f, 0.f, 0.f}, s2 = {0.f, 0.f, 0.f, 0.f};
    for (int r = 0; r < 48; ++r) {
        f32x4 v = *reinterpret_cast<const f32x4*>(y + (size_t)(n0 + r) * CC + cq * 4);
        #pragma unroll
        for (int e = 0; e < 4; ++e) { s[e] += v[e]; s2[e] += v[e] * v[e]; }
    }
    __shared__ f32x4 ls[256], ls2[256];
    ls[t] = s; ls2[t] = s2;
    __syncthreads();
    if (t < 32) {
        f32x4 S = ls[t], S2 = ls2[t];
        #pragma unroll
        for (int g = 1; g < 8; ++g) {
            f32x4 a = ls[g * 32 + t], b = ls2[g * 32 + t];
            #pragma unroll
            for (int e = 0; e < 4; ++e) { S[e] += a[e]; S2[e] += b[e]; }
        }
        float* base = partials + (size_t)blockIdx.x * 256;
        *reinterpret_cast<f32x4*>(base + t * 4) = S;
        *reinterpret_cast<f32x4*>(base + 128 + t * 4) = S2;
    }
}

// BN stats stage 2: finalize scale/shift per channel.
__global__ __launch_bounds__(128)
void k_bnfin(const float* __restrict__ partials, const float* __restrict__ g,
             const float* __restrict__ b, float* __restrict__ scsh)
{
    int c = threadIdx.x;
    float S = 0.f, S2 = 0.f;
    for (int blk = 0; blk < 48; ++blk) {
        S  += partials[(size_t)blk * 256 + c];
        S2 += partials[(size_t)blk * 256 + 128 + c];
    }
    const float inv = 1.f / (float)NN;
    float mu = S * inv;
    float var = S2 * inv - mu * mu;
    float sc = g[c] * rsqrtf(var + 1e-5f);
    scsh[c] = sc;
    scsh[128 + c] = b[c] - mu * sc;
}

// BN apply + ReLU: y f32 [n][128] -> h bf16 [n][128]
__global__ __launch_bounds__(256)
void k_bnrelu(const float* __restrict__ y, const float* __restrict__ scsh,
              unsigned short* __restrict__ h)
{
    int gid = blockIdx.x * 256 + threadIdx.x;   // quads; total 589824
    int c0 = (gid * 4) & 127;
    f32x4 v = *reinterpret_cast<const f32x4*>(y + (size_t)gid * 4);
    us4 st;
    #pragma unroll
    for (int r = 0; r < 4; ++r) {
        float f = fmaxf(fmaf(v[r], scsh[c0 + r], scsh[128 + c0 + r]), 0.f);
        st[r] = f2bf(f);
    }
    *reinterpret_cast<us4*>(h + (size_t)gid * 4) = st;
}

// ---------------------------------------------------------------------------
// Local channel self-attention. qkv bf16 [n][384] (q pre-scaled), att bf16 [n][128].
// Thread = (n, head). dots[nch][m] = sum_kk q[nch]@(p+kk) * k[m]@(p+kk);
// softmax over m; out[nch] = sum_m attn * boxsum3x3(V[m]).
// m processed in two halves of 8 with online softmax to bound registers.
// ---------------------------------------------------------------------------
__global__ __launch_bounds__(256, 2)
void k_attn(const unsigned short* __restrict__ qkv, unsigned short* __restrict__ att)
{
    int gid = blockIdx.x * 256 + threadIdx.x;   // 147456
    int head = gid & 7;
    int n = gid >> 3;
    int b = n / PP, pix = n - b * PP;
    int i = pix / WW, j = pix % WW;

    int noff[9]; bool val[9];
    #pragma unroll
    for (int dy = 0; dy < 3; ++dy)
        #pragma unroll
        for (int dx = 0; dx < 3; ++dx) {
            int kk = dy * 3 + dx;
            val[kk] = ((unsigned)(i + dy - 1) < (unsigned)HH) &&
                      ((unsigned)(j + dx - 1) < (unsigned)WW);
            noff[kk] = (dy - 1) * WW + (dx - 1);
        }

    int hc = head * 16;

    // box sums of V (16 channels)
    float vs[16];
    #pragma unroll
    for (int m = 0; m < 16; ++m) vs[m] = 0.f;
    #pragma unroll
    for (int kk = 0; kk < 9; ++kk) {
        if (!val[kk]) continue;
        const unsigned short* vp = qkv + (size_t)(n + noff[kk]) * 384 + 256 + hc;
        us8 v0 = *reinterpret_cast<const us8*>(vp);
        us8 v1 = *reinterpret_cast<const us8*>(vp + 8);
        #pragma unroll
        for (int e = 0; e < 8; ++e) { vs[e] += bf2f(v0[e]); vs[8 + e] += bf2f(v1[e]); }
    }

    float mrun[16], lrun[16], orun[16];
    #pragma unroll
    for (int q = 0; q < 16; ++q) { mrun[q] = -3e38f; lrun[q] = 0.f; orun[q] = 0.f; }

    #pragma unroll
    for (int mh = 0; mh < 2; ++mh) {
        float kv[9][8];
        #pragma unroll
        for (int kk = 0; kk < 9; ++kk) {
            if (val[kk]) {
                const unsigned short* kp = qkv + (size_t)(n + noff[kk]) * 384 + 128 + hc + mh * 8;
                us8 kr = *reinterpret_cast<const us8*>(kp);
                #pragma unroll
                for (int e = 0; e < 8; ++e) kv[kk][e] = bf2f(kr[e]);
            } else {
                #pragma unroll
                for (int e = 0; e < 8; ++e) kv[kk][e] = 0.f;
            }
        }
        #pragma unroll
        for (int nch = 0; nch < 16; ++nch) {
            float qv[9];
            #pragma unroll
            for (int kk = 0; kk < 9; ++kk)
                qv[kk] = val[kk] ? bf2f(qkv[(size_t)(n + noff[kk]) * 384 + hc + nch]) : 0.f;
            float d[8];
            #pragma unroll
            for (int m = 0; m < 8; ++m) d[m] = 0.f;
            #pragma unroll
            for (int kk = 0; kk < 9; ++kk)
                #pragma unroll
                for (int m = 0; m < 8; ++m)
                    d[m] = fmaf(qv[kk], kv[kk][m], d[m]);
            float mx = d[0];
            #pragma unroll
            for (int m = 1; m < 8; ++m) mx = fmaxf(mx, d[m]);
            float mnew = fmaxf(mrun[nch], mx);
            float corr = __expf(mrun[nch] - mnew);
            float l = lrun[nch] * corr, o = orun[nch] * corr;
            #pragma unroll
            for (int m = 0; m < 8; ++m) {
                float e = __expf(d[m] - mnew);
                l += e;
                o = fmaf(e, vs[mh * 8 + m], o);
            }
            mrun[nch] = mnew; lrun[nch] = l; orun[nch] = o;
        }
    }

    unsigned short* ob = att + (size_t)n * CC + hc;
    #pragma unroll
    for (int t2 = 0; t2 < 8; ++t2) {
        unsigned lo = f2bf(orun[2 * t2] / lrun[2 * t2]);
        unsigned hi = f2bf(orun[2 * t2 + 1] / lrun[2 * t2 + 1]);
        *reinterpret_cast<unsigned*>(ob + 2 * t2) = lo | (hi << 16);
    }
}

// ---------------------------------------------------------------------------
extern "C" void kernel_launch(void* const* d_in, const int* in_sizes, int n_in,
                              void* d_out, int out_size, void* d_ws, size_t ws_size,
                              hipStream_t stream)
{
    const float* x      = (const float*)d_in[0];
    const float* w_in   = (const float*)d_in[1];
    const float* b_in   = (const float*)d_in[2];
    const float* conv_w = (const float*)d_in[3];
    const float* conv_b = (const float*)d_in[4];  // absorbed by BN mean — unused
    const float* bn_g   = (const float*)d_in[5];
    const float* bn_b   = (const float*)d_in[6];
    const float* qkv_w  = (const float*)d_in[7];
    const float* fc_w   = (const float*)d_in[8];
    const float* fc_b   = (const float*)d_in[9];
    const float* w_out  = (const float*)d_in[10];
    const float* b_out  = (const float*)d_in[11];
    (void)conv_b;

    char* ws = (char*)d_ws;
    unsigned short* zp    = (unsigned short*)(ws);                   // 4 KB zeros
    unsigned short* wcv   = (unsigned short*)(ws + 4096);            // 589824*2
    unsigned short* wqkv  = (unsigned short*)(ws + 1183744);         // 196608*2
    unsigned short* wfc   = (unsigned short*)(ws + 1576960);         // 65536*2
    unsigned short* wi    = (unsigned short*)(ws + 1708032);         // 8192*2
    unsigned short* wo    = (unsigned short*)(ws + 1724416);         // 8192*2
    unsigned short* xT    = (unsigned short*)(ws + 1740800);         // 18432*64*2
    unsigned short* bufA  = (unsigned short*)(ws + 4100096);         // 18432*128*2
    float*          ybuf  = (float*)        (ws + 8818688);          // 18432*128*4
    unsigned short* hbuf  = (unsigned short*)(ws + 18255872);        // 18432*128*2
    unsigned short* qkvb  = (unsigned short*)(ws + 22974464);        // 18432*384*2
    unsigned short* attb  = (unsigned short*)(ws + 37130240);        // 18432*128*2
    float*          parts = (float*)        (ws + 41848832);         // 48*256*4
    float*          scsh  = (float*)        (ws + 41897984);         // 256*4

    hipMemsetAsync(zp, 0, 4096, stream);

    k_wconv<<<3392, 256, 0, stream>>>(conv_w, qkv_w, fc_w, w_in, w_out,
                                      wcv, wqkv, wfc, wi, wo);
    k_xconv<<<NN / 256, 256, 0, stream>>>(x, xT);

    // in-proj: 64 -> 128, bias, bf16 out -> bufA
    k_gemm<2, 2, 0, 0><<<dim3(96, 1), 256, 0, stream>>>(
        wi, xT, b_in, nullptr, bufA, nullptr, 64, 64, 128);

    for (int L = 0; L < 4; ++L) {
        const unsigned short* wc = wcv + (size_t)L * 147456;
        // dilated conv3x3 -> ybuf (f32), bias dropped (BN absorbs)
        switch (L) {
            case 0: k_gemm<2, 2, 1, 1><<<dim3(96, 1), 256, 0, stream>>>(
                        wc, bufA, nullptr, nullptr, ybuf, zp, 1152, 128, 128); break;
            case 1: k_gemm<2, 2, 1, 2><<<dim3(96, 1), 256, 0, stream>>>(
                        wc, bufA, nullptr, nullptr, ybuf, zp, 1152, 128, 128); break;
            case 2: k_gemm<2, 2, 1, 4><<<dim3(96, 1), 256, 0, stream>>>(
                        wc, bufA, nullptr, nullptr, ybuf, zp, 1152, 128, 128); break;
            case 3: k_gemm<2, 2, 1, 8><<<dim3(96, 1), 256, 0, stream>>>(
                        wc, bufA, nullptr, nullptr, ybuf, zp, 1152, 128, 128); break;
        }
        k_bnpart<<<48, 256, 0, stream>>>(ybuf, parts);
        k_bnfin<<<1, 128, 0, stream>>>(parts, bn_g + L * 128, bn_b + L * 128, scsh);
        k_bnrelu<<<2304, 256, 0, stream>>>(ybuf, scsh, hbuf);

        // qkv: 128 -> 384 (q scale folded into weights) -> qkvb
        k_gemm<2, 2, 0, 0><<<dim3(96, 3), 256, 0, stream>>>(
            wqkv + (size_t)L * 49152, hbuf, nullptr, nullptr, qkvb, nullptr, 128, 128, 384);

        k_attn<<<576, 256, 0, stream>>>(qkvb, attb);

        // fc: 128 -> 128 + bias + residual(hbuf) -> bufA (next conv input)
        k_gemm<2, 2, 2, 0><<<dim3(96, 1), 256, 0, stream>>>(
            wfc + (size_t)L * 16384, attb, fc_b + L * 128, hbuf, bufA, nullptr, 128, 128, 128);
    }

    // out-proj: 128 -> 64, bias, f32 scatter to d_out [b][64][9216]
    k_gemm<1, 4, 3, 0><<<dim3(48, 1), 256, 0, stream>>>(
        wo, bufA, b_out, nullptr, (float*)d_out, nullptr, 128, 128, 64);
}

// Round 4
// 562.049 us; speedup vs baseline: 9.3394x; 2.7226x over previous
//
#include <hip/hip_runtime.h>
#include <math.h>

typedef __attribute__((ext_vector_type(8))) short bf16x8;
typedef __attribute__((ext_vector_type(4))) float f32x4;
typedef __attribute__((ext_vector_type(4))) unsigned short us4;
typedef __attribute__((ext_vector_type(8))) unsigned short us8;

constexpr int BB = 2;
constexpr int CC = 128;
constexpr int HH = 96, WW = 96;
constexpr int PP = HH * WW;        // 9216
constexpr int NN = BB * PP;        // 18432 pixels total
constexpr size_t PLANE_F = (size_t)NN * CC;   // 2359296 floats per partial plane

__device__ __forceinline__ float bf2f(unsigned short u) {
    return __uint_as_float(((unsigned)u) << 16);
}
__device__ __forceinline__ unsigned short f2bf(float f) {
    unsigned u = __float_as_uint(f);
    unsigned r = u + 0x7fff + ((u >> 16) & 1);
    return (unsigned short)(r >> 16);
}

// ---------------------------------------------------------------------------
// Weight conversion / reordering to bf16 (one dispatch).
// conv_w[L][o][c][ky][kx] -> wcv[L][o][t*128+c]  (t = ky*3+kx)
// qkv_w -> bf16 with q-rows (o<128) scaled by 0.25; fc/w_in/w_out direct.
// ---------------------------------------------------------------------------
__global__ __launch_bounds__(256)
void k_wconv(const float* __restrict__ conv_w, const float* __restrict__ qkv_w,
             const float* __restrict__ fc_w, const float* __restrict__ w_in,
             const float* __restrict__ w_out,
             unsigned short* __restrict__ wcv, unsigned short* __restrict__ wqkv,
             unsigned short* __restrict__ wfc, unsigned short* __restrict__ wi,
             unsigned short* __restrict__ wo)
{
    int gid = blockIdx.x * 256 + threadIdx.x;
    if (gid < 589824) {
        int L = gid / 147456, r = gid % 147456;
        int o = r / 1152, k = r % 1152;
        int t = k / 128, c = k % 128;
        float v = conv_w[(((size_t)(L * 128 + o) * 128 + c) * 9) + t];
        wcv[gid] = f2bf(v);
    } else if (gid < 786432) {
        int g = gid - 589824;
        int o = (g % 49152) / 128;
        float v = qkv_w[g] * (o < 128 ? 0.25f : 1.0f);
        wqkv[g] = f2bf(v);
    } else if (gid < 851968) {
        int g = gid - 786432;
        wfc[g] = f2bf(fc_w[g]);
    } else if (gid < 860160) {
        int g = gid - 851968;
        wi[g] = f2bf(w_in[g]);
    } else if (gid < 868352) {
        int g = gid - 860160;
        wo[g] = f2bf(w_out[g]);
    }
}

// x (fp32 [b][64][9216]) -> xT (bf16 [n][64])
__global__ __launch_bounds__(256)
void k_xconv(const float* __restrict__ x, unsigned short* __restrict__ xT)
{
    int n = blockIdx.x * 256 + threadIdx.x;
    int b = n / PP, p = n - b * PP;
    unsigned short* dst = xT + (size_t)n * 64;
    #pragma unroll
    for (int cg = 0; cg < 16; ++cg) {
        us4 st;
        #pragma unroll
        for (int r = 0; r < 4; ++r)
            st[r] = f2bf(x[((size_t)(b * 64 + cg * 4 + r)) * PP + p]);
        *reinterpret_cast<us4*>(dst + cg * 4) = st;
    }
}

// ---------------------------------------------------------------------------
// MFMA GEMM: out[o][n] = sum_k W[o][k] * act[n][k]   (act [n][Cin] bf16)
// Wave tile 64(M) x 96(N). Block = WM x WN waves.
// MODE 0: bf16 out [n][Cout] (+bias)
// MODE 1: f32 partial out, plane selected by blockIdx.z (conv K-split; bias
//         dropped, BN absorbs)
// MODE 2: bf16 out [n][Cout] + bias + bf16 residual
// MODE 3: f32 out [b][Cout][9216] scatter + bias (final projection)
// DIL>0: implicit dilated 3x3 conv; this block handles taps [3z, 3z+3).
// ---------------------------------------------------------------------------
template<int WM, int WN, int MODE, int DIL>
__global__ __launch_bounds__(WM * WN * 64)
void k_gemm(const unsigned short* __restrict__ W,
            const unsigned short* __restrict__ act,
            const float* __restrict__ bias,
            const unsigned short* __restrict__ resid,
            void* __restrict__ outp,
            const unsigned short* __restrict__ zp,
            int Kw, int Cin, int Cout)
{
    int tid = threadIdx.x;
    int lane = tid & 63, wv = tid >> 6;
    int wm = wv % WM, wn = wv / WM;
    int l15 = lane & 15, kg = lane >> 4;

    int n_base = blockIdx.x * (WN * 96) + wn * 96;
    int o_base = blockIdx.y * (WM * 64) + wm * 64;

    const unsigned short* wbase[4];
    #pragma unroll
    for (int fm = 0; fm < 4; ++fm) {
        int o = o_base + fm * 16 + l15;
        wbase[fm] = W + (size_t)o * Kw + kg * 8;
    }

    const unsigned short* bbase[6];
    int iF[6], jF[6];
    #pragma unroll
    for (int fn = 0; fn < 6; ++fn) {
        int n = n_base + fn * 16 + l15;
        bbase[fn] = act + (size_t)n * Cin + kg * 8;
        if (DIL > 0) {
            int pix = n % PP;
            iF[fn] = pix / WW;
            jF[fn] = pix % WW;
        }
    }

    f32x4 acc[4][6];
    #pragma unroll
    for (int fm = 0; fm < 4; ++fm)
        #pragma unroll
        for (int fn = 0; fn < 6; ++fn)
            acc[fm][fn] = (f32x4){0.f, 0.f, 0.f, 0.f};

    if constexpr (DIL > 0) {
        const unsigned short* zpk = zp + kg * 8;
        int t0 = blockIdx.z * 3;
        for (int t = t0; t < t0 + 3; ++t) {
            int oy = (t / 3 - 1) * DIL, ox = (t % 3 - 1) * DIL;
            int disp = (oy * WW + ox) * Cin;
            const unsigned short* baddr[6];
            #pragma unroll
            for (int fn = 0; fn < 6; ++fn) {
                bool v = ((unsigned)(iF[fn] + oy) < (unsigned)HH) &&
                         ((unsigned)(jF[fn] + ox) < (unsigned)WW);
                baddr[fn] = v ? (bbase[fn] + disp) : zpk;
            }
            #pragma unroll
            for (int c0 = 0; c0 < 128; c0 += 32) {
                bf16x8 a[4], b[6];
                #pragma unroll
                for (int fm = 0; fm < 4; ++fm)
                    a[fm] = *reinterpret_cast<const bf16x8*>(wbase[fm] + t * 128 + c0);
                #pragma unroll
                for (int fn = 0; fn < 6; ++fn)
                    b[fn] = *reinterpret_cast<const bf16x8*>(baddr[fn] + c0);
                #pragma unroll
                for (int fm = 0; fm < 4; ++fm)
                    #pragma unroll
                    for (int fn = 0; fn < 6; ++fn)
                        acc[fm][fn] = __builtin_amdgcn_mfma_f32_16x16x32_bf16(
                            a[fm], b[fn], acc[fm][fn], 0, 0, 0);
            }
        }
    } else {
        #pragma unroll
        for (int k0 = 0; k0 < 128; k0 += 32) {
            if (k0 >= Cin) break;
            bf16x8 a[4], b[6];
            #pragma unroll
            for (int fm = 0; fm < 4; ++fm)
                a[fm] = *reinterpret_cast<const bf16x8*>(wbase[fm] + k0);
            #pragma unroll
            for (int fn = 0; fn < 6; ++fn)
                b[fn] = *reinterpret_cast<const bf16x8*>(bbase[fn] + k0);
            #pragma unroll
            for (int fm = 0; fm < 4; ++fm)
                #pragma unroll
                for (int fn = 0; fn < 6; ++fn)
                    acc[fm][fn] = __builtin_amdgcn_mfma_f32_16x16x32_bf16(
                        a[fm], b[fn], acc[fm][fn], 0, 0, 0);
        }
    }

    // Epilogue. D-frag: col n = l15, rows o = o_base+fm*16+kg*4+r
    #pragma unroll
    for (int fm = 0; fm < 4; ++fm) {
        #pragma unroll
        for (int fn = 0; fn < 6; ++fn) {
            f32x4 v = acc[fm][fn];
            int n = n_base + fn * 16 + l15;
            int o0 = o_base + fm * 16 + kg * 4;
            if constexpr (MODE == 1) {
                float* op = (float*)outp + (size_t)blockIdx.z * PLANE_F;
                *reinterpret_cast<f32x4*>(op + (size_t)n * Cout + o0) = v;
            } else if constexpr (MODE == 0 || MODE == 2) {
                if (bias) {
                    #pragma unroll
                    for (int r = 0; r < 4; ++r) v[r] += bias[o0 + r];
                }
                if constexpr (MODE == 2) {
                    us4 rv = *reinterpret_cast<const us4*>(resid + (size_t)n * Cout + o0);
                    #pragma unroll
                    for (int r = 0; r < 4; ++r) v[r] += bf2f(rv[r]);
                }
                us4 st;
                #pragma unroll
                for (int r = 0; r < 4; ++r) st[r] = f2bf(v[r]);
                *reinterpret_cast<us4*>((unsigned short*)outp + (size_t)n * Cout + o0) = st;
            } else {
                int b_ = n / PP, p = n - b_ * PP;
                float* op = (float*)outp;
                #pragma unroll
                for (int r = 0; r < 4; ++r)
                    op[((size_t)(b_ * Cout + o0 + r)) * PP + p] = v[r] + bias[o0 + r];
            }
        }
    }
}

// ---------------------------------------------------------------------------
// BN stats stage 1 over 3 K-split partial planes.
// ---------------------------------------------------------------------------
__global__ __launch_bounds__(256)
void k_bnpart(const float* __restrict__ y, float* __restrict__ partials)
{
    int t = threadIdx.x;
    int cq = t & 31, ng = t >> 5;
    int n0 = blockIdx.x * 384 + ng * 48;
    f32x4 s = {0.f, 0.f, 0.f, 0.f}, s2 = {0.f, 0.f, 0.f, 0.f};
    for (int r = 0; r < 48; ++r) {
        size_t idx = (size_t)(n0 + r) * CC + cq * 4;
        f32x4 a = *reinterpret_cast<const f32x4*>(y + idx);
        f32x4 b = *reinterpret_cast<const f32x4*>(y + PLANE_F + idx);
        f32x4 c = *reinterpret_cast<const f32x4*>(y + 2 * PLANE_F + idx);
        #pragma unroll
        for (int e = 0; e < 4; ++e) {
            float v = a[e] + b[e] + c[e];
            s[e] += v; s2[e] += v * v;
        }
    }
    __shared__ f32x4 ls[256], ls2[256];
    ls[t] = s; ls2[t] = s2;
    __syncthreads();
    if (t < 32) {
        f32x4 S = ls[t], S2 = ls2[t];
        #pragma unroll
        for (int g = 1; g < 8; ++g) {
            f32x4 a = ls[g * 32 + t], b = ls2[g * 32 + t];
            #pragma unroll
            for (int e = 0; e < 4; ++e) { S[e] += a[e]; S2[e] += b[e]; }
        }
        float* base = partials + (size_t)blockIdx.x * 256;
        *reinterpret_cast<f32x4*>(base + t * 4) = S;
        *reinterpret_cast<f32x4*>(base + 128 + t * 4) = S2;
    }
}

__global__ __launch_bounds__(128)
void k_bnfin(const float* __restrict__ partials, const float* __restrict__ g,
             const float* __restrict__ b, float* __restrict__ scsh)
{
    int c = threadIdx.x;
    float S = 0.f, S2 = 0.f;
    for (int blk = 0; blk < 48; ++blk) {
        S  += partials[(size_t)blk * 256 + c];
        S2 += partials[(size_t)blk * 256 + 128 + c];
    }
    const float inv = 1.f / (float)NN;
    float mu = S * inv;
    float var = S2 * inv - mu * mu;
    float sc = g[c] * rsqrtf(var + 1e-5f);
    scsh[c] = sc;
    scsh[128 + c] = b[c] - mu * sc;
}

// BN apply + ReLU over summed planes: -> h bf16 [n][128]
__global__ __launch_bounds__(256)
void k_bnrelu(const float* __restrict__ y, const float* __restrict__ scsh,
              unsigned short* __restrict__ h)
{
    int gid = blockIdx.x * 256 + threadIdx.x;   // quads
    int c0 = (gid * 4) & 127;
    size_t idx = (size_t)gid * 4;
    f32x4 a = *reinterpret_cast<const f32x4*>(y + idx);
    f32x4 b = *reinterpret_cast<const f32x4*>(y + PLANE_F + idx);
    f32x4 c = *reinterpret_cast<const f32x4*>(y + 2 * PLANE_F + idx);
    us4 st;
    #pragma unroll
    for (int r = 0; r < 4; ++r) {
        float v = a[r] + b[r] + c[r];
        float f = fmaxf(fmaf(v, scsh[c0 + r], scsh[128 + c0 + r]), 0.f);
        st[r] = f2bf(f);
    }
    *reinterpret_cast<us4*>(h + idx) = st;
}

// ---------------------------------------------------------------------------
// Local channel self-attention, spill-free.
// Thread = (pixel n, head, ng): owns 4 q-channels vs all 16 m-channels.
// dots[nn][m] = sum_kk q(p+kk)[nn] * k(p+kk)[m]; softmax over m;
// out[nn] = sum_m attn[nn][m] * boxsum3x3(V[m]).
// ---------------------------------------------------------------------------
__global__ __launch_bounds__(256)
void k_attn(const unsigned short* __restrict__ qkv, unsigned short* __restrict__ att)
{
    int gid = blockIdx.x * 256 + threadIdx.x;   // 589824
    int ng   = gid & 3;
    int head = (gid >> 2) & 7;
    int n    = gid >> 5;
    int pix = n % PP;
    int i = pix / WW, j = pix % WW;
    int hc = head * 16;
    const unsigned short* base = qkv + (size_t)n * 384;

    float dots[4][16];
    float vs[16];
    #pragma unroll
    for (int m = 0; m < 16; ++m) vs[m] = 0.f;
    #pragma unroll
    for (int nn = 0; nn < 4; ++nn)
        #pragma unroll
        for (int m = 0; m < 16; ++m) dots[nn][m] = 0.f;

    #pragma unroll
    for (int dy = 0; dy < 3; ++dy) {
        #pragma unroll
        for (int dx = 0; dx < 3; ++dx) {
            if (!(((unsigned)(i + dy - 1) < (unsigned)HH) &&
                  ((unsigned)(j + dx - 1) < (unsigned)WW))) continue;
            const unsigned short* pb = base + ((dy - 1) * WW + (dx - 1)) * 384;
            us4 q4 = *reinterpret_cast<const us4*>(pb + hc + ng * 4);
            us8 k0 = *reinterpret_cast<const us8*>(pb + 128 + hc);
            us8 k1 = *reinterpret_cast<const us8*>(pb + 128 + hc + 8);
            us8 v0 = *reinterpret_cast<const us8*>(pb + 256 + hc);
            us8 v1 = *reinterpret_cast<const us8*>(pb + 256 + hc + 8);
            float kf[16];
            #pragma unroll
            for (int e = 0; e < 8; ++e) {
                kf[e] = bf2f(k0[e]);
                kf[8 + e] = bf2f(k1[e]);
                vs[e] += bf2f(v0[e]);
                vs[8 + e] += bf2f(v1[e]);
            }
            #pragma unroll
            for (int nn = 0; nn < 4; ++nn) {
                float qf = bf2f(q4[nn]);
                #pragma unroll
                for (int m = 0; m < 16; ++m)
                    dots[nn][m] = fmaf(qf, kf[m], dots[nn][m]);
            }
        }
    }

    us4 st;
    #pragma unroll
    for (int nn = 0; nn < 4; ++nn) {
        float mx = dots[nn][0];
        #pragma unroll
        for (int m = 1; m < 16; ++m) mx = fmaxf(mx, dots[nn][m]);
        float den = 0.f, o = 0.f;
        #pragma unroll
        for (int m = 0; m < 16; ++m) {
            float e = __expf(dots[nn][m] - mx);
            den += e;
            o = fmaf(e, vs[m], o);
        }
        st[nn] = f2bf(o / den);
    }
    *reinterpret_cast<us4*>(att + (size_t)n * CC + hc + ng * 4) = st;
}

// ---------------------------------------------------------------------------
extern "C" void kernel_launch(void* const* d_in, const int* in_sizes, int n_in,
                              void* d_out, int out_size, void* d_ws, size_t ws_size,
                              hipStream_t stream)
{
    const float* x      = (const float*)d_in[0];
    const float* w_in   = (const float*)d_in[1];
    const float* b_in   = (const float*)d_in[2];
    const float* conv_w = (const float*)d_in[3];
    const float* bn_g   = (const float*)d_in[5];
    const float* bn_b   = (const float*)d_in[6];
    const float* qkv_w  = (const float*)d_in[7];
    const float* fc_w   = (const float*)d_in[8];
    const float* fc_b   = (const float*)d_in[9];
    const float* w_out  = (const float*)d_in[10];
    const float* b_out  = (const float*)d_in[11];

    char* ws = (char*)d_ws;
    unsigned short* zp    = (unsigned short*)(ws);                   // 4 KB zeros
    unsigned short* wcv   = (unsigned short*)(ws + 4096);
    unsigned short* wqkv  = (unsigned short*)(ws + 1183744);
    unsigned short* wfc   = (unsigned short*)(ws + 1576960);
    unsigned short* wi    = (unsigned short*)(ws + 1708032);
    unsigned short* wo    = (unsigned short*)(ws + 1724416);
    unsigned short* xT    = (unsigned short*)(ws + 1740800);
    unsigned short* bufA  = (unsigned short*)(ws + 4100096);
    float*          ybuf  = (float*)        (ws + 8818688);          // 3 planes f32
    unsigned short* attb  = (unsigned short*)(ws + 8818688);         // aliases plane0 (dead)
    unsigned short* qkvb  = (unsigned short*)(ws + 18255872);        // aliases planes1-2 (dead)
    unsigned short* hbuf  = (unsigned short*)(ws + 37130240);
    float*          parts = (float*)        (ws + 41848832);
    float*          scsh  = (float*)        (ws + 41897984);

    hipMemsetAsync(zp, 0, 4096, stream);

    k_wconv<<<3392, 256, 0, stream>>>(conv_w, qkv_w, fc_w, w_in, w_out,
                                      wcv, wqkv, wfc, wi, wo);
    k_xconv<<<NN / 256, 256, 0, stream>>>(x, xT);

    // in-proj: 64 -> 128, bias -> bufA (bf16)
    k_gemm<1, 2, 0, 0><<<dim3(96, 2), 128, 0, stream>>>(
        wi, xT, b_in, nullptr, bufA, nullptr, 64, 64, 128);

    for (int L = 0; L < 4; ++L) {
        const unsigned short* wc = wcv + (size_t)L * 147456;
        // dilated conv3x3 -> 3 f32 partial planes (K-split by tap group)
        switch (L) {
            case 0: k_gemm<2, 2, 1, 1><<<dim3(96, 1, 3), 256, 0, stream>>>(
                        wc, bufA, nullptr, nullptr, ybuf, zp, 1152, 128, 128); break;
            case 1: k_gemm<2, 2, 1, 2><<<dim3(96, 1, 3), 256, 0, stream>>>(
                        wc, bufA, nullptr, nullptr, ybuf, zp, 1152, 128, 128); break;
            case 2: k_gemm<2, 2, 1, 4><<<dim3(96, 1, 3), 256, 0, stream>>>(
                        wc, bufA, nullptr, nullptr, ybuf, zp, 1152, 128, 128); break;
            case 3: k_gemm<2, 2, 1, 8><<<dim3(96, 1, 3), 256, 0, stream>>>(
                        wc, bufA, nullptr, nullptr, ybuf, zp, 1152, 128, 128); break;
        }
        k_bnpart<<<48, 256, 0, stream>>>(ybuf, parts);
        k_bnfin<<<1, 128, 0, stream>>>(parts, bn_g + L * 128, bn_b + L * 128, scsh);
        k_bnrelu<<<2304, 256, 0, stream>>>(ybuf, scsh, hbuf);

        // qkv: 128 -> 384 -> qkvb
        k_gemm<1, 2, 0, 0><<<dim3(96, 6), 128, 0, stream>>>(
            wqkv + (size_t)L * 49152, hbuf, nullptr, nullptr, qkvb, nullptr, 128, 128, 384);

        k_attn<<<2304, 256, 0, stream>>>(qkvb, attb);

        // fc: 128 -> 128 + bias + residual(hbuf) -> bufA
        k_gemm<1, 2, 2, 0><<<dim3(96, 2), 128, 0, stream>>>(
            wfc + (size_t)L * 16384, attb, fc_b + L * 128, hbuf, bufA, nullptr, 128, 128, 128);
    }

    // out-proj: 128 -> 64, bias, f32 scatter to d_out
    k_gemm<1, 4, 3, 0><<<dim3(48, 1), 256, 0, stream>>>(
        wo, bufA, b_out, nullptr, (float*)d_out, nullptr, 128, 128, 64);
}